// Round 13
// baseline (91.925 us; speedup 1.0000x reference)
//
#include <hip/hip_runtime.h>
#include <cmath>

#define B_ 2
#define N_ 2048
#define C_ 128
#define H_ 8
#define D_ 16
#define CI_ 512
#define NROW 4096

typedef float f32x4 __attribute__((ext_vector_type(4)));
typedef short bf16x4 __attribute__((ext_vector_type(4)));
typedef unsigned short u16;

__device__ __forceinline__ float sigmoidf_(float x) {
    return 1.0f / (1.0f + __expf(-x));
}

__device__ __forceinline__ u16 f2bf(float x) {
    union { float f; unsigned int u; } v; v.f = x;
    unsigned int r = v.u + 0x7fffu + ((v.u >> 16) & 1u);
    return (u16)(r >> 16);
}

__device__ __forceinline__ float bf2f(u16 b) {
    union { unsigned int u; float f; } v; v.u = ((unsigned int)b) << 16;
    return v.f;
}

__device__ __forceinline__ float exp2_fast(float x) {
#if __has_builtin(__builtin_amdgcn_exp2f)
    return __builtin_amdgcn_exp2f(x);
#else
    return __expf(x * 0.6931471806f);
#endif
}

__device__ __forceinline__ f32x4 mfma16(bf16x4 a, bf16x4 b, f32x4 c) {
#if __has_builtin(__builtin_amdgcn_mfma_f32_16x16x16bf16_1k)
    return __builtin_amdgcn_mfma_f32_16x16x16bf16_1k(a, b, c, 0, 0, 0);
#else
    asm("v_mfma_f32_16x16x16_bf16 %0, %1, %2, %0\n\ts_nop 7\n\ts_nop 3"
        : "+v"(c) : "v"(a), "v"(b));
    return c;
#endif
}

// Weight regions (u16 elements). FRAGMENT-MAJOR layout:
// wF[((ct*KK + kk)*64 + lane)*4 + e] = W^T[ct*16 + (lane&15)][kk*16 + 4*(lane>>4) + e]
#define WT_QS    0
#define WT_QB    16384
#define WT_WQ    32768
#define WT_WG    49152
#define WT_KS    65536
#define WT_KB    81920
#define WT_WK    98304
#define WT_WV    114688
#define WT_AZIT  131072
#define WT_AZIC  147456
#define WT_TS    163840
#define WT_TB    180224
#define WT_TAZIC 196608
#define WT_GLU1  212992
#define WT_GLU2  278528
#define WT_TAZIT 344064
#define WT_TOTAL 409600

// ---------------- K0: convert weights to bf16 fragment-major tiles ----------------
__global__ __launch_bounds__(256)
void prep_kernel(const float* qs_w, const float* qb_w, const float* wq, const float* wg,
                 const float* ks_w, const float* kb_w, const float* wk, const float* wv,
                 const float* azi_wt, const float* azi_wc, const float* ts_w, const float* tb_w,
                 const float* tazi_wc, const float* glu1, const float* glu2, const float* tazi_wt,
                 u16* wT)
{
    __shared__ float lds[16 * 512];
    const int blk = blockIdx.x;
    const float* src; int width, kk, KK; u16* dst;
    if (blk < 104) {
        int m = blk >> 3; kk = blk & 7;
        const float* srcs[13] = {qs_w, qb_w, wq, wg, ks_w, kb_w, wk, wv,
                                 azi_wt, azi_wc, ts_w, tb_w, tazi_wc};
        src = srcs[m]; width = 128; KK = 8;
        dst = wT + m * 16384;
    } else if (blk < 112) {
        kk = blk - 104; src = glu1; width = 512; KK = 8; dst = wT + WT_GLU1;
    } else if (blk < 120) {
        kk = blk - 112; src = glu2; width = 512; KK = 8; dst = wT + WT_GLU2;
    } else {
        kk = blk - 120; src = tazi_wt; width = 128; KK = 32; dst = wT + WT_TAZIT;
    }
    const int t = threadIdx.x;
    const int w4 = width >> 2;
    for (int idx = t; idx < 16 * w4; idx += 256) {
        int r = idx / w4, c4 = (idx % w4) * 4;
        *(float4*)&lds[r * width + c4] =
            *(const float4*)(src + (size_t)(kk * 16 + r) * width + c4);
    }
    __syncthreads();
    const int CT = width >> 4;
    for (int it = t; it < CT * 64; it += 256) {
        int ct = it >> 6, l = it & 63;
        int j15 = l & 15, gg = l >> 4;
        u16 e0 = f2bf(lds[(4 * gg + 0) * width + ct * 16 + j15]);
        u16 e1 = f2bf(lds[(4 * gg + 1) * width + ct * 16 + j15]);
        u16 e2 = f2bf(lds[(4 * gg + 2) * width + ct * 16 + j15]);
        u16 e3 = f2bf(lds[(4 * gg + 3) * width + ct * 16 + j15]);
        uint2 pk;
        pk.x = (unsigned)e0 | ((unsigned)e1 << 16);
        pk.y = (unsigned)e2 | ((unsigned)e3 << 16);
        *(uint2*)(dst + ((size_t)(ct * KK + kk) * 64 + l) * 4) = pk;
    }
}

// ---------------- K1: fused AdaLN + projections, 32 rows/block, 512 thr ----------------
__global__ __launch_bounds__(512)
void adaln_mfma(const float* __restrict__ x_q, const float* __restrict__ scq,
                const float* __restrict__ x_k, const float* __restrict__ sck,
                const float* __restrict__ q_cond_w, const float* __restrict__ q_scale_b,
                const float* __restrict__ bq,
                const float* __restrict__ k_cond_w, const float* __restrict__ k_scale_b,
                const u16* __restrict__ wT,
                u16* __restrict__ qs, u16* __restrict__ ks, u16* __restrict__ vt,
                float* __restrict__ gate)
{
    __shared__ u16 xn[32][132];
    __shared__ u16 cn[32][132];
    __shared__ u16 xq[32][132];
    __shared__ u16 vls[128][40];
    const int bi = blockIdx.x;            // 256 blocks
    const int qside = (bi < 128) ? 1 : 0;
    const int rowblk = (bi & 127) * 32;
    const float* xin = qside ? x_q : x_k;
    const float* cin = qside ? scq : sck;
    const float* cw  = qside ? q_cond_w : k_cond_w;
    const float* slb = qside ? q_scale_b : k_scale_b;
    const u16* Wsc = wT + (qside ? WT_QS : WT_KS);
    const u16* Wbi = wT + (qside ? WT_QB : WT_KB);
    const u16* W1  = wT + (qside ? WT_WQ : WT_WK);
    const u16* W2  = wT + (qside ? WT_WG : WT_WV);

    const int t = threadIdx.x;
    {   // LN: 16 lanes/row, 8 elems/lane, 32 rows
        const int r = t >> 4, p = t & 15;
        const size_t base = (size_t)(rowblk + r) * 128 + p * 8;
        float xv[8], cv[8];
        *(float4*)&xv[0] = *(const float4*)(xin + base);
        *(float4*)&xv[4] = *(const float4*)(xin + base + 4);
        *(float4*)&cv[0] = *(const float4*)(cin + base);
        *(float4*)&cv[4] = *(const float4*)(cin + base + 4);
        float sx = 0, sxx = 0, sc = 0, scc = 0;
#pragma unroll
        for (int u = 0; u < 8; u++) {
            sx += xv[u]; sxx += xv[u] * xv[u];
            sc += cv[u]; scc += cv[u] * cv[u];
        }
#pragma unroll
        for (int off = 1; off < 16; off <<= 1) {
            sx += __shfl_xor(sx, off); sxx += __shfl_xor(sxx, off);
            sc += __shfl_xor(sc, off); scc += __shfl_xor(scc, off);
        }
        const float inv = 1.0f / 128.0f;
        float mx = sx * inv, vx = sxx * inv - mx * mx, rx = rsqrtf(vx + 1e-5f);
        float mc = sc * inv, vc = scc * inv - mc * mc, rc = rsqrtf(vc + 1e-5f);
#pragma unroll
        for (int u4 = 0; u4 < 2; u4++) {
            bf16x4 xw, cwv;
#pragma unroll
            for (int i = 0; i < 4; i++) {
                int e = p * 8 + u4 * 4 + i;
                xw[i]  = (short)f2bf((xv[u4 * 4 + i] - mx) * rx);
                cwv[i] = (short)f2bf((cv[u4 * 4 + i] - mc) * rc * cw[e]);
            }
            *(bf16x4*)&xn[r][p * 8 + u4 * 4] = xw;
            *(bf16x4*)&cn[r][p * 8 + u4 * 4] = cwv;
        }
    }
    __syncthreads();

    const int lane = t & 63, w = t >> 6;       // 8 waves, ct = w
    const int j15 = lane & 15, g = lane >> 4;
    const int c = w * 16 + j15;

    // GEMM1: adaptive scale + bias, 2 row-halves per wave
    f32x4 as0 = (f32x4)0.f, as1 = (f32x4)0.f, ab0 = (f32x4)0.f, ab1 = (f32x4)0.f;
#pragma unroll
    for (int kk = 0; kk < 8; kk++) {
        bf16x4 a0 = *(bf16x4*)&cn[j15][kk * 16 + 4 * g];
        bf16x4 a1 = *(bf16x4*)&cn[16 + j15][kk * 16 + 4 * g];
        bf16x4 bs = *(const bf16x4*)(Wsc + ((size_t)(w * 8 + kk) * 64 + lane) * 4);
        bf16x4 bb = *(const bf16x4*)(Wbi + ((size_t)(w * 8 + kk) * 64 + lane) * 4);
        as0 = mfma16(a0, bs, as0);  as1 = mfma16(a1, bs, as1);
        ab0 = mfma16(a0, bb, ab0);  ab1 = mfma16(a1, bb, ab1);
    }
    {
        float sb = slb[c];
#pragma unroll
        for (int reg = 0; reg < 4; reg++) {
            int nl = 4 * g + reg;
            xq[nl][c]      = f2bf(sigmoidf_(as0[reg] + sb) * bf2f(xn[nl][c]) + ab0[reg]);
            xq[16 + nl][c] = f2bf(sigmoidf_(as1[reg] + sb) * bf2f(xn[16 + nl][c]) + ab1[reg]);
        }
    }
    __syncthreads();

    // GEMM2: w1 (q/k), w2 (gate/v)
    f32x4 o10 = (f32x4)0.f, o11 = (f32x4)0.f, o20 = (f32x4)0.f, o21 = (f32x4)0.f;
#pragma unroll
    for (int kk = 0; kk < 8; kk++) {
        bf16x4 a0 = *(bf16x4*)&xq[j15][kk * 16 + 4 * g];
        bf16x4 a1 = *(bf16x4*)&xq[16 + j15][kk * 16 + 4 * g];
        bf16x4 b1 = *(const bf16x4*)(W1 + ((size_t)(w * 8 + kk) * 64 + lane) * 4);
        bf16x4 b2 = *(const bf16x4*)(W2 + ((size_t)(w * 8 + kk) * 64 + lane) * 4);
        o10 = mfma16(a0, b1, o10);  o11 = mfma16(a1, b1, o11);
        o20 = mfma16(a0, b2, o20);  o21 = mfma16(a1, b2, o21);
    }
    const int b = rowblk >> 11, n0 = rowblk & 2047;
    if (qside) {
        float bqv = bq[c];
#pragma unroll
        for (int reg = 0; reg < 4; reg++) {
            int n_a = n0 + 4 * g + reg, n_b = n_a + 16;
            qs[(((size_t)b * 8 + w) * 2048 + n_a) * 16 + j15] = f2bf((o10[reg] + bqv) * 0.25f);
            qs[(((size_t)b * 8 + w) * 2048 + n_b) * 16 + j15] = f2bf((o11[reg] + bqv) * 0.25f);
            gate[((size_t)b * 2048 + n_a) * 128 + c] = sigmoidf_(o20[reg]);
            gate[((size_t)b * 2048 + n_b) * 128 + c] = sigmoidf_(o21[reg]);
        }
    } else {
#pragma unroll
        for (int reg = 0; reg < 4; reg++) {
            int n_a = n0 + 4 * g + reg, n_b = n_a + 16;
            ks[(((size_t)b * 8 + w) * 2048 + n_a) * 16 + j15] = f2bf(o10[reg]);
            ks[(((size_t)b * 8 + w) * 2048 + n_b) * 16 + j15] = f2bf(o11[reg]);
            vls[c][4 * g + reg]      = f2bf(o20[reg]);
            vls[c][16 + 4 * g + reg] = f2bf(o21[reg]);
        }
        __syncthreads();
        const int cc = t & 127, qtr = t >> 7;   // qtr 0..3 -> 8 n each
        const int h = cc >> 4, d = cc & 15;
        unsigned pk[4];
#pragma unroll
        for (int u2 = 0; u2 < 4; u2++)
            pk[u2] = (unsigned)vls[cc][qtr * 8 + 2 * u2] |
                     ((unsigned)vls[cc][qtr * 8 + 2 * u2 + 1] << 16);
        u16* vp = vt + ((size_t)(b * 8 + h) * 16 + d) * 2048 + n0 + qtr * 8;
        *(uint4*)vp = *(uint4*)pk;
    }
}

// ---------------- K2: MFMA attention, 4-way key split, deep pipeline, no fences ----------------
// Pair prefetch depth 3, K/V depth 2. No asm waitcnt / sched_barrier: compiler
// inserts its own lgkmcnt for the PS write->read dependency and keeps the
// prefetch buffers live in VGPRs (budget ~120 <= 128 cap from (256,4)).
__global__ __launch_bounds__(256, 4)
void attn_kernel(const u16* __restrict__ qg, const u16* __restrict__ kg,
                 const u16* __restrict__ vtg, const float* __restrict__ pair,
                 const float* __restrict__ gate, float* __restrict__ ao)
{
    __shared__ float SM[4 * 1088 + 64];
    const int t = threadIdx.x;
    const int l = t & 63, w = t >> 6;
    const int g = l >> 4, q = l & 15;
    const int wid = (blockIdx.x & 7) * 256 + (blockIdx.x >> 3);
    const int qt = wid & 127;
    const int bh = wid >> 7;
    const int b = bh >> 3, h = bh & 7;
    const int q0 = qt * 16;
    float* PS = SM + w * 1088;
    float* lsumL = SM + 4352;

    const u16* qb = qg + ((size_t)bh * 2048 + q0 + q) * 16 + 4 * g;
    const u16* kb = kg + ((size_t)bh * 2048 + q) * 16 + 4 * g;
    const u16* vb = vtg + ((size_t)bh * 16 + q) * 2048 + 4 * g;
    const float* pb = pair + (size_t)bh * N_ * N_ + (size_t)(q0 + g) * N_ + q * 4;

    bf16x4 qf = *(const bf16x4*)qb;

    f32x4 o = {0.f, 0.f, 0.f, 0.f};
    float lsum = 0.f;
    const int base = w * 8;

    f32x4 p0[4], p1[4], p2[4];
    bf16x4 k0[4], v0[4], k1[4], v1[4];

    auto issue_pair = [&](f32x4 (&pr)[4], int kt) {
        const float* pt = pb + kt * 64;
#pragma unroll
        for (int i = 0; i < 4; i++)
            pr[i] = *(const f32x4*)(pt + (size_t)(4 * i) * N_);
    };
    auto issue_kv = [&](bf16x4 (&kf)[4], bf16x4 (&vf)[4], int kt) {
#pragma unroll
        for (int tt = 0; tt < 4; tt++) {
            kf[tt] = *(const bf16x4*)(kb + (size_t)(kt * 64 + tt * 16) * 16);
            vf[tt] = *(const bf16x4*)(vb + kt * 64 + tt * 16);
        }
    };
    auto step = [&](f32x4 (&pr)[4], bf16x4 (&kf)[4], bf16x4 (&vf)[4]) {
#pragma unroll
        for (int i = 0; i < 4; i++)
            *(f32x4*)&PS[(g + 4 * i) * 68 + q * 4] = pr[i];
        f32x4 s[4];
#pragma unroll
        for (int tt = 0; tt < 4; tt++) {
            f32x4 c = *(const f32x4*)&PS[q * 68 + tt * 16 + 4 * g];
            s[tt] = mfma16(kf[tt], qf, c);
        }
        bf16x4 pf[4];
        float ls = 0.f;
#pragma unroll
        for (int tt = 0; tt < 4; tt++) {
#pragma unroll
            for (int r = 0; r < 4; r++) {
                float pe = exp2_fast(fmaf(s[tt][r], 1.442695041f, -11.54156033f));
                ls += pe;
                pf[tt][r] = (short)(__float_as_uint(pe) >> 16);
            }
        }
        lsum += ls;
#pragma unroll
        for (int tt = 0; tt < 4; tt++)
            o = mfma16(pf[tt], vf[tt], o);
    };

    issue_pair(p0, base);     issue_pair(p1, base + 1); issue_pair(p2, base + 2);
    issue_kv(k0, v0, base);   issue_kv(k1, v1, base + 1);

    step(p0, k0, v0); issue_pair(p0, base + 3); issue_kv(k0, v0, base + 2);
    step(p1, k1, v1); issue_pair(p1, base + 4); issue_kv(k1, v1, base + 3);
    step(p2, k0, v0); issue_pair(p2, base + 5); issue_kv(k0, v0, base + 4);
    step(p0, k1, v1); issue_pair(p0, base + 6); issue_kv(k1, v1, base + 5);
    step(p1, k0, v0); issue_pair(p1, base + 7); issue_kv(k0, v0, base + 6);
    step(p2, k1, v1);                           issue_kv(k1, v1, base + 7);
    step(p0, k0, v0);
    step(p1, k1, v1);

    lsum += __shfl_xor(lsum, 16);
    lsum += __shfl_xor(lsum, 32);
    if (l < 16) lsumL[w * 16 + l] = lsum;

    float* oLw = PS;
#pragma unroll
    for (int r = 0; r < 4; r++)
        oLw[(4 * g + r) * 17 + q] = o[r];
    __syncthreads();

    const int row = t >> 4, d = t & 15;
    float osum = 0.f, lt = 0.f;
#pragma unroll
    for (int ww = 0; ww < 4; ww++) {
        osum += SM[ww * 1088 + row * 17 + d];
        lt   += lsumL[ww * 16 + row];
    }
    size_t idx = ((size_t)b * 2048 + q0 + row) * 128 + h * 16 + d;
    ao[idx] = osum * (1.0f / lt) * gate[idx];
}

// ---------------- K3: fused post-attention + transition, fragment-major weights ----------------
__global__ __launch_bounds__(512)
void post_trans(const float* __restrict__ aob, const float* __restrict__ scq,
                const float* __restrict__ x_q,
                const float* __restrict__ azi_bc, const float* __restrict__ t_cond_w,
                const float* __restrict__ t_scale_b, const float* __restrict__ t_azi_bc,
                const u16* __restrict__ wT, float* __restrict__ out)
{
    __shared__ u16 aoL[16][132];
    __shared__ u16 scL[16][132];
    __shared__ u16 cnL[16][132];
    __shared__ u16 ynL[16][132];
    __shared__ u16 aaL[16][132];
    __shared__ float yL[16][132];
    __shared__ u16 hL[16][520];
    const int rowblk = blockIdx.x * 16;
    const int t = threadIdx.x, lane = t & 63, w = t >> 6;   // 8 waves
    const int j15 = lane & 15, g = lane >> 4;
    const int c = w * 16 + j15;

    {   // P0
        const int r = t >> 5, p = t & 31;
        const size_t base = (size_t)(rowblk + r) * 128 + p * 4;
        float av[4], cv[4], xv[4];
        *(float4*)&av[0] = *(const float4*)(aob + base);
        *(float4*)&cv[0] = *(const float4*)(scq + base);
        *(float4*)&xv[0] = *(const float4*)(x_q + base);
        float sc = 0, scc = 0;
#pragma unroll
        for (int u = 0; u < 4; u++) { sc += cv[u]; scc += cv[u] * cv[u]; }
#pragma unroll
        for (int off = 1; off < 32; off <<= 1) {
            sc += __shfl_xor(sc, off); scc += __shfl_xor(scc, off);
        }
        const float inv = 1.0f / 128.0f;
        float mc = sc * inv, vc = scc * inv - mc * mc, rc = rsqrtf(vc + 1e-5f);
#pragma unroll
        for (int u = 0; u < 4; u++) {
            int e = p * 4 + u;
            aoL[r][e] = f2bf(av[u]);
            scL[r][e] = f2bf(cv[u]);
            cnL[r][e] = f2bf((cv[u] - mc) * rc * t_cond_w[e]);
            yL[r][e]  = xv[u];
        }
    }
    __syncthreads();

    // Merged GEMM-A+B: 5 streams, 1 ct per wave
    f32x4 at_ = (f32x4)0.f, ac_ = (f32x4)0.f;
    f32x4 s_  = (f32x4)0.f, b_  = (f32x4)0.f, gg_ = (f32x4)0.f;
    {
        const u16* Bt = wT + WT_AZIT;
        const u16* Bc = wT + WT_AZIC;
        const u16* Bs = wT + WT_TS;
        const u16* Bb = wT + WT_TB;
        const u16* Bg = wT + WT_TAZIC;
#pragma unroll
        for (int kk = 0; kk < 8; kk++) {
            size_t fo = ((size_t)(w * 8 + kk) * 64 + lane) * 4;
            bf16x4 a_ao = *(bf16x4*)&aoL[j15][kk * 16 + 4 * g];
            bf16x4 a_sc = *(bf16x4*)&scL[j15][kk * 16 + 4 * g];
            bf16x4 a_cn = *(bf16x4*)&cnL[j15][kk * 16 + 4 * g];
            bf16x4 bt  = *(const bf16x4*)(Bt + fo);
            bf16x4 bc2 = *(const bf16x4*)(Bc + fo);
            bf16x4 bs  = *(const bf16x4*)(Bs + fo);
            bf16x4 bb  = *(const bf16x4*)(Bb + fo);
            bf16x4 bg  = *(const bf16x4*)(Bg + fo);
            at_ = mfma16(a_ao, bt,  at_);
            ac_ = mfma16(a_sc, bc2, ac_);
            s_  = mfma16(a_cn, bs,  s_);
            b_  = mfma16(a_cn, bb,  b_);
            gg_ = mfma16(a_sc, bg,  gg_);
        }
    }
    {
        float bc0 = azi_bc[c];
#pragma unroll
        for (int reg = 0; reg < 4; reg++) {
            int nl = 4 * g + reg;
            yL[nl][c] = yL[nl][c] + sigmoidf_(ac_[reg] + bc0) * at_[reg];
        }
    }
    __syncthreads();

    {   // LN(y)
        const int r = t >> 5, p = t & 31;
        float yv[4];
        *(float4*)&yv[0] = *(float4*)&yL[r][p * 4];
        float sy = 0, syy = 0;
#pragma unroll
        for (int u = 0; u < 4; u++) { sy += yv[u]; syy += yv[u] * yv[u]; }
#pragma unroll
        for (int off = 1; off < 32; off <<= 1) {
            sy += __shfl_xor(sy, off); syy += __shfl_xor(syy, off);
        }
        const float inv = 1.0f / 128.0f;
        float my = sy * inv, vy = syy * inv - my * my, ry = rsqrtf(vy + 1e-5f);
#pragma unroll
        for (int u = 0; u < 4; u++)
            ynL[r][p * 4 + u] = f2bf((yv[u] - my) * ry);
    }
    __syncthreads();

    f32x4 tg_;
    {
        float sb = t_scale_b[c], tb = t_azi_bc[c];
#pragma unroll
        for (int reg = 0; reg < 4; reg++) {
            int nl = 4 * g + reg;
            aaL[nl][c] = f2bf(sigmoidf_(s_[reg] + sb) * bf2f(ynL[nl][c]) + b_[reg]);
            tg_[reg] = sigmoidf_(gg_[reg] + tb);
        }
    }
    __syncthreads();

    // GEMM-C
    {
        const u16* G1 = wT + WT_GLU1;
        const u16* G2 = wT + WT_GLU2;
        f32x4 h1_[4], h2_[4];
#pragma unroll
        for (int i = 0; i < 4; i++) { h1_[i] = (f32x4)0.f; h2_[i] = (f32x4)0.f; }
#pragma unroll
        for (int kk = 0; kk < 8; kk++) {
            bf16x4 a = *(bf16x4*)&aaL[j15][kk * 16 + 4 * g];
#pragma unroll
            for (int u = 0; u < 4; u++) {
                size_t fo = ((size_t)((w * 4 + u) * 8 + kk) * 64 + lane) * 4;
                bf16x4 b1 = *(const bf16x4*)(G1 + fo);
                bf16x4 b2 = *(const bf16x4*)(G2 + fo);
                h1_[u] = mfma16(a, b1, h1_[u]);
                h2_[u] = mfma16(a, b2, h2_[u]);
            }
        }
#pragma unroll
        for (int u = 0; u < 4; u++) {
            int cc = (w * 4 + u) * 16 + j15;
#pragma unroll
            for (int reg = 0; reg < 4; reg++) {
                int nl = 4 * g + reg;
                float hv1 = h1_[u][reg];
                hL[nl][cc] = f2bf(hv1 * sigmoidf_(hv1) * h2_[u][reg]);
            }
        }
    }
    __syncthreads();

    // GEMM-D
    f32x4 td[4];
#pragma unroll
    for (int i = 0; i < 4; i++) td[i] = (f32x4)0.f;
    {
        const u16* W4 = wT + WT_TAZIT;
#pragma unroll
        for (int kk = 0; kk < 32; kk++) {
            bf16x4 a = *(bf16x4*)&hL[j15][kk * 16 + 4 * g];
            bf16x4 b = *(const bf16x4*)(W4 + ((size_t)(w * 32 + kk) * 64 + lane) * 4);
            td[kk & 3] = mfma16(a, b, td[kk & 3]);
        }
    }
#pragma unroll
    for (int reg = 0; reg < 4; reg++) {
        int nl = 4 * g + reg;
        size_t gi = (size_t)(rowblk + nl) * 128 + c;
        out[gi] = yL[nl][c] + tg_[reg] * (td[0][reg] + td[1][reg] + td[2][reg] + td[3][reg]);
    }
}

extern "C" void kernel_launch(void* const* d_in, const int* in_sizes, int n_in,
                              void* d_out, int out_size, void* d_ws, size_t ws_size,
                              hipStream_t stream)
{
    (void)in_sizes; (void)n_in; (void)out_size; (void)ws_size;
    const float* x_q      = (const float*)d_in[0];
    const float* x_k      = (const float*)d_in[1];
    const float* pair     = (const float*)d_in[4];
    const float* scq      = (const float*)d_in[5];
    const float* sck      = (const float*)d_in[6];
    const float* q_cond_w = (const float*)d_in[7];
    const float* q_scale_w= (const float*)d_in[8];
    const float* q_scale_b= (const float*)d_in[9];
    const float* q_bias_w = (const float*)d_in[10];
    const float* k_cond_w = (const float*)d_in[11];
    const float* k_scale_w= (const float*)d_in[12];
    const float* k_scale_b= (const float*)d_in[13];
    const float* k_bias_w = (const float*)d_in[14];
    const float* wq       = (const float*)d_in[15];
    const float* bq       = (const float*)d_in[16];
    const float* wk       = (const float*)d_in[17];
    const float* wv       = (const float*)d_in[18];
    const float* wg       = (const float*)d_in[19];
    const float* azi_wt   = (const float*)d_in[20];
    const float* azi_wc   = (const float*)d_in[21];
    const float* azi_bc   = (const float*)d_in[22];
    const float* t_cond_w = (const float*)d_in[23];
    const float* t_scale_w= (const float*)d_in[24];
    const float* t_scale_b= (const float*)d_in[25];
    const float* t_bias_w = (const float*)d_in[26];
    const float* glu1     = (const float*)d_in[27];
    const float* glu2     = (const float*)d_in[28];
    const float* t_azi_wt = (const float*)d_in[29];
    const float* t_azi_wc = (const float*)d_in[30];
    const float* t_azi_bc = (const float*)d_in[31];

    float* out = (float*)d_out;
    u16* qs = (u16*)d_ws;                    // bf16 [16][2048][16]   1MB
    u16* ks = qs + 524288;                   // 1MB
    u16* vt = ks + 524288;                   // bf16 [16][16][2048]   1MB
    float* gate = (float*)(vt + 524288);     // f32 [4096][128]       2MB
    float* aob  = gate + 524288;             // f32 [4096][128]       2MB
    u16* wT = (u16*)(aob + 524288);          // bf16 weights (fragment-major) 0.8MB

    prep_kernel<<<152, 256, 0, stream>>>(
        q_scale_w, q_bias_w, wq, wg, k_scale_w, k_bias_w, wk, wv,
        azi_wt, azi_wc, t_scale_w, t_bias_w, t_azi_wc, glu1, glu2, t_azi_wt, wT);
    adaln_mfma<<<256, 512, 0, stream>>>(
        x_q, scq, x_k, sck, q_cond_w, q_scale_b, bq, k_cond_w, k_scale_b,
        wT, qs, ks, vt, gate);
    attn_kernel<<<B_ * H_ * (N_ / 16), 256, 0, stream>>>(qs, ks, vt, pair, gate, aob);
    post_trans<<<NROW / 16, 512, 0, stream>>>(
        aob, scq, x_q, azi_bc, t_cond_w, t_scale_b, t_azi_bc, wT, out);
}

// Round 14
// 86.585 us; speedup vs baseline: 1.0617x; 1.0617x over previous
//
#include <hip/hip_runtime.h>
#include <cmath>

#define B_ 2
#define N_ 2048
#define C_ 128
#define H_ 8
#define D_ 16
#define CI_ 512
#define NROW 4096

typedef float f32x4 __attribute__((ext_vector_type(4)));
typedef short bf16x4 __attribute__((ext_vector_type(4)));
typedef unsigned short u16;

__device__ __forceinline__ float sigmoidf_(float x) {
    return 1.0f / (1.0f + __expf(-x));
}

__device__ __forceinline__ u16 f2bf(float x) {
    union { float f; unsigned int u; } v; v.f = x;
    unsigned int r = v.u + 0x7fffu + ((v.u >> 16) & 1u);
    return (u16)(r >> 16);
}

__device__ __forceinline__ float bf2f(u16 b) {
    union { unsigned int u; float f; } v; v.u = ((unsigned int)b) << 16;
    return v.f;
}

__device__ __forceinline__ float exp2_fast(float x) {
#if __has_builtin(__builtin_amdgcn_exp2f)
    return __builtin_amdgcn_exp2f(x);
#else
    return __expf(x * 0.6931471806f);
#endif
}

__device__ __forceinline__ f32x4 mfma16(bf16x4 a, bf16x4 b, f32x4 c) {
#if __has_builtin(__builtin_amdgcn_mfma_f32_16x16x16bf16_1k)
    return __builtin_amdgcn_mfma_f32_16x16x16bf16_1k(a, b, c, 0, 0, 0);
#else
    asm("v_mfma_f32_16x16x16_bf16 %0, %1, %2, %0\n\ts_nop 7\n\ts_nop 3"
        : "+v"(c) : "v"(a), "v"(b));
    return c;
#endif
}

// Weight regions (u16 elements). FRAGMENT-MAJOR layout:
// wF[((ct*KK + kk)*64 + lane)*4 + e] = W^T[ct*16 + (lane&15)][kk*16 + 4*(lane>>4) + e]
#define WT_QS    0
#define WT_QB    16384
#define WT_WQ    32768
#define WT_WG    49152
#define WT_KS    65536
#define WT_KB    81920
#define WT_WK    98304
#define WT_WV    114688
#define WT_AZIT  131072
#define WT_AZIC  147456
#define WT_TS    163840
#define WT_TB    180224
#define WT_TAZIC 196608
#define WT_GLU1  212992
#define WT_GLU2  278528
#define WT_TAZIT 344064
#define WT_TOTAL 409600

// ---------------- K0: convert weights to bf16 fragment-major tiles ----------------
__global__ __launch_bounds__(256)
void prep_kernel(const float* qs_w, const float* qb_w, const float* wq, const float* wg,
                 const float* ks_w, const float* kb_w, const float* wk, const float* wv,
                 const float* azi_wt, const float* azi_wc, const float* ts_w, const float* tb_w,
                 const float* tazi_wc, const float* glu1, const float* glu2, const float* tazi_wt,
                 u16* wT)
{
    __shared__ float lds[16 * 512];
    const int blk = blockIdx.x;
    const float* src; int width, kk, KK; u16* dst;
    if (blk < 104) {
        int m = blk >> 3; kk = blk & 7;
        const float* srcs[13] = {qs_w, qb_w, wq, wg, ks_w, kb_w, wk, wv,
                                 azi_wt, azi_wc, ts_w, tb_w, tazi_wc};
        src = srcs[m]; width = 128; KK = 8;
        dst = wT + m * 16384;
    } else if (blk < 112) {
        kk = blk - 104; src = glu1; width = 512; KK = 8; dst = wT + WT_GLU1;
    } else if (blk < 120) {
        kk = blk - 112; src = glu2; width = 512; KK = 8; dst = wT + WT_GLU2;
    } else {
        kk = blk - 120; src = tazi_wt; width = 128; KK = 32; dst = wT + WT_TAZIT;
    }
    const int t = threadIdx.x;
    const int w4 = width >> 2;
    for (int idx = t; idx < 16 * w4; idx += 256) {
        int r = idx / w4, c4 = (idx % w4) * 4;
        *(float4*)&lds[r * width + c4] =
            *(const float4*)(src + (size_t)(kk * 16 + r) * width + c4);
    }
    __syncthreads();
    const int CT = width >> 4;
    for (int it = t; it < CT * 64; it += 256) {
        int ct = it >> 6, l = it & 63;
        int j15 = l & 15, gg = l >> 4;
        u16 e0 = f2bf(lds[(4 * gg + 0) * width + ct * 16 + j15]);
        u16 e1 = f2bf(lds[(4 * gg + 1) * width + ct * 16 + j15]);
        u16 e2 = f2bf(lds[(4 * gg + 2) * width + ct * 16 + j15]);
        u16 e3 = f2bf(lds[(4 * gg + 3) * width + ct * 16 + j15]);
        uint2 pk;
        pk.x = (unsigned)e0 | ((unsigned)e1 << 16);
        pk.y = (unsigned)e2 | ((unsigned)e3 << 16);
        *(uint2*)(dst + ((size_t)(ct * KK + kk) * 64 + l) * 4) = pk;
    }
}

// ---------------- K1: fused AdaLN + projections, 32 rows/block, 512 thr ----------------
__global__ __launch_bounds__(512)
void adaln_mfma(const float* __restrict__ x_q, const float* __restrict__ scq,
                const float* __restrict__ x_k, const float* __restrict__ sck,
                const float* __restrict__ q_cond_w, const float* __restrict__ q_scale_b,
                const float* __restrict__ bq,
                const float* __restrict__ k_cond_w, const float* __restrict__ k_scale_b,
                const u16* __restrict__ wT,
                u16* __restrict__ qs, u16* __restrict__ ks, u16* __restrict__ vt,
                u16* __restrict__ gate)
{
    __shared__ u16 xn[32][132];
    __shared__ u16 cn[32][132];
    __shared__ u16 xq[32][132];
    __shared__ u16 vls[128][40];
    const int bi = blockIdx.x;            // 256 blocks
    const int qside = (bi < 128) ? 1 : 0;
    const int rowblk = (bi & 127) * 32;
    const float* xin = qside ? x_q : x_k;
    const float* cin = qside ? scq : sck;
    const float* cw  = qside ? q_cond_w : k_cond_w;
    const float* slb = qside ? q_scale_b : k_scale_b;
    const u16* Wsc = wT + (qside ? WT_QS : WT_KS);
    const u16* Wbi = wT + (qside ? WT_QB : WT_KB);
    const u16* W1  = wT + (qside ? WT_WQ : WT_WK);
    const u16* W2  = wT + (qside ? WT_WG : WT_WV);

    const int t = threadIdx.x;
    {   // LN: 16 lanes/row, 8 elems/lane, 32 rows
        const int r = t >> 4, p = t & 15;
        const size_t base = (size_t)(rowblk + r) * 128 + p * 8;
        float xv[8], cv[8];
        *(float4*)&xv[0] = *(const float4*)(xin + base);
        *(float4*)&xv[4] = *(const float4*)(xin + base + 4);
        *(float4*)&cv[0] = *(const float4*)(cin + base);
        *(float4*)&cv[4] = *(const float4*)(cin + base + 4);
        float sx = 0, sxx = 0, sc = 0, scc = 0;
#pragma unroll
        for (int u = 0; u < 8; u++) {
            sx += xv[u]; sxx += xv[u] * xv[u];
            sc += cv[u]; scc += cv[u] * cv[u];
        }
#pragma unroll
        for (int off = 1; off < 16; off <<= 1) {
            sx += __shfl_xor(sx, off); sxx += __shfl_xor(sxx, off);
            sc += __shfl_xor(sc, off); scc += __shfl_xor(scc, off);
        }
        const float inv = 1.0f / 128.0f;
        float mx = sx * inv, vx = sxx * inv - mx * mx, rx = rsqrtf(vx + 1e-5f);
        float mc = sc * inv, vc = scc * inv - mc * mc, rc = rsqrtf(vc + 1e-5f);
#pragma unroll
        for (int u4 = 0; u4 < 2; u4++) {
            bf16x4 xw, cwv;
#pragma unroll
            for (int i = 0; i < 4; i++) {
                int e = p * 8 + u4 * 4 + i;
                xw[i]  = (short)f2bf((xv[u4 * 4 + i] - mx) * rx);
                cwv[i] = (short)f2bf((cv[u4 * 4 + i] - mc) * rc * cw[e]);
            }
            *(bf16x4*)&xn[r][p * 8 + u4 * 4] = xw;
            *(bf16x4*)&cn[r][p * 8 + u4 * 4] = cwv;
        }
    }
    __syncthreads();

    const int lane = t & 63, w = t >> 6;       // 8 waves, ct = w
    const int j15 = lane & 15, g = lane >> 4;
    const int c = w * 16 + j15;

    // GEMM1: adaptive scale + bias, 2 row-halves per wave
    f32x4 as0 = (f32x4)0.f, as1 = (f32x4)0.f, ab0 = (f32x4)0.f, ab1 = (f32x4)0.f;
#pragma unroll
    for (int kk = 0; kk < 8; kk++) {
        bf16x4 a0 = *(bf16x4*)&cn[j15][kk * 16 + 4 * g];
        bf16x4 a1 = *(bf16x4*)&cn[16 + j15][kk * 16 + 4 * g];
        bf16x4 bs = *(const bf16x4*)(Wsc + ((size_t)(w * 8 + kk) * 64 + lane) * 4);
        bf16x4 bb = *(const bf16x4*)(Wbi + ((size_t)(w * 8 + kk) * 64 + lane) * 4);
        as0 = mfma16(a0, bs, as0);  as1 = mfma16(a1, bs, as1);
        ab0 = mfma16(a0, bb, ab0);  ab1 = mfma16(a1, bb, ab1);
    }
    {
        float sb = slb[c];
#pragma unroll
        for (int reg = 0; reg < 4; reg++) {
            int nl = 4 * g + reg;
            xq[nl][c]      = f2bf(sigmoidf_(as0[reg] + sb) * bf2f(xn[nl][c]) + ab0[reg]);
            xq[16 + nl][c] = f2bf(sigmoidf_(as1[reg] + sb) * bf2f(xn[16 + nl][c]) + ab1[reg]);
        }
    }
    __syncthreads();

    // GEMM2: w1 (q/k), w2 (gate/v)
    f32x4 o10 = (f32x4)0.f, o11 = (f32x4)0.f, o20 = (f32x4)0.f, o21 = (f32x4)0.f;
#pragma unroll
    for (int kk = 0; kk < 8; kk++) {
        bf16x4 a0 = *(bf16x4*)&xq[j15][kk * 16 + 4 * g];
        bf16x4 a1 = *(bf16x4*)&xq[16 + j15][kk * 16 + 4 * g];
        bf16x4 b1 = *(const bf16x4*)(W1 + ((size_t)(w * 8 + kk) * 64 + lane) * 4);
        bf16x4 b2 = *(const bf16x4*)(W2 + ((size_t)(w * 8 + kk) * 64 + lane) * 4);
        o10 = mfma16(a0, b1, o10);  o11 = mfma16(a1, b1, o11);
        o20 = mfma16(a0, b2, o20);  o21 = mfma16(a1, b2, o21);
    }
    const int b = rowblk >> 11, n0 = rowblk & 2047;
    if (qside) {
        float bqv = bq[c];
#pragma unroll
        for (int reg = 0; reg < 4; reg++) {
            int n_a = n0 + 4 * g + reg, n_b = n_a + 16;
            qs[(((size_t)b * 8 + w) * 2048 + n_a) * 16 + j15] = f2bf((o10[reg] + bqv) * 0.25f);
            qs[(((size_t)b * 8 + w) * 2048 + n_b) * 16 + j15] = f2bf((o11[reg] + bqv) * 0.25f);
            gate[((size_t)b * 2048 + n_a) * 128 + c] = f2bf(sigmoidf_(o20[reg]));
            gate[((size_t)b * 2048 + n_b) * 128 + c] = f2bf(sigmoidf_(o21[reg]));
        }
    } else {
#pragma unroll
        for (int reg = 0; reg < 4; reg++) {
            int n_a = n0 + 4 * g + reg, n_b = n_a + 16;
            ks[(((size_t)b * 8 + w) * 2048 + n_a) * 16 + j15] = f2bf(o10[reg]);
            ks[(((size_t)b * 8 + w) * 2048 + n_b) * 16 + j15] = f2bf(o11[reg]);
            vls[c][4 * g + reg]      = f2bf(o20[reg]);
            vls[c][16 + 4 * g + reg] = f2bf(o21[reg]);
        }
        __syncthreads();
        const int cc = t & 127, qtr = t >> 7;   // qtr 0..3 -> 8 n each
        const int h = cc >> 4, d = cc & 15;
        unsigned pk[4];
#pragma unroll
        for (int u2 = 0; u2 < 4; u2++)
            pk[u2] = (unsigned)vls[cc][qtr * 8 + 2 * u2] |
                     ((unsigned)vls[cc][qtr * 8 + 2 * u2 + 1] << 16);
        u16* vp = vt + ((size_t)(b * 8 + h) * 16 + d) * 2048 + n0 + qtr * 8;
        *(uint4*)vp = *(uint4*)pk;
    }
}

// ---------------- K2: MFMA attention (R12-exact structure; bf16 gate/ao) ----------------
__global__ __launch_bounds__(256, 4)
void attn_kernel(const u16* __restrict__ qg, const u16* __restrict__ kg,
                 const u16* __restrict__ vtg, const float* __restrict__ pair,
                 const u16* __restrict__ gate, u16* __restrict__ ao)
{
    __shared__ float SM[4 * 1088 + 64];
    const int t = threadIdx.x;
    const int l = t & 63, w = t >> 6;
    const int g = l >> 4, q = l & 15;
    const int wid = (blockIdx.x & 7) * 256 + (blockIdx.x >> 3);
    const int qt = wid & 127;
    const int bh = wid >> 7;
    const int b = bh >> 3, h = bh & 7;
    const int q0 = qt * 16;
    float* PS = SM + w * 1088;
    float* lsumL = SM + 4352;

    const u16* qb = qg + ((size_t)bh * 2048 + q0 + q) * 16 + 4 * g;
    const u16* kb = kg + ((size_t)bh * 2048 + q) * 16 + 4 * g;
    const u16* vb = vtg + ((size_t)bh * 16 + q) * 2048 + 4 * g;
    const float* pb = pair + (size_t)bh * N_ * N_ + (size_t)(q0 + g) * N_ + q * 4;

    bf16x4 qf = *(const bf16x4*)qb;

    f32x4 o = {0.f, 0.f, 0.f, 0.f};
    float lsum = 0.f;
    const int base = w * 8, kend = base + 8;

    f32x4 p0[4], p1[4];
    bf16x4 k0[4], v0[4], k1[4], v1[4];

    auto issue_pair = [&](f32x4 (&pr)[4], int kt) {
        const float* pt = pb + kt * 64;
#pragma unroll
        for (int i = 0; i < 4; i++)
            pr[i] = *(const f32x4*)(pt + (size_t)(4 * i) * N_);
    };
    auto issue_kv = [&](bf16x4 (&kf)[4], bf16x4 (&vf)[4], int kt) {
#pragma unroll
        for (int tt = 0; tt < 4; tt++) {
            kf[tt] = *(const bf16x4*)(kb + (size_t)(kt * 64 + tt * 16) * 16);
            vf[tt] = *(const bf16x4*)(vb + kt * 64 + tt * 16);
        }
    };
    auto step = [&](f32x4 (&pr)[4], bf16x4 (&kf)[4], bf16x4 (&vf)[4]) {
#pragma unroll
        for (int i = 0; i < 4; i++)
            *(f32x4*)&PS[(g + 4 * i) * 68 + q * 4] = pr[i];
        asm volatile("s_waitcnt lgkmcnt(0)" ::: "memory");
        __builtin_amdgcn_sched_barrier(0);
        f32x4 s[4];
#pragma unroll
        for (int tt = 0; tt < 4; tt++) {
            f32x4 c = *(const f32x4*)&PS[q * 68 + tt * 16 + 4 * g];
            s[tt] = mfma16(kf[tt], qf, c);
        }
        bf16x4 pf[4];
        float ls = 0.f;
#pragma unroll
        for (int tt = 0; tt < 4; tt++) {
#pragma unroll
            for (int r = 0; r < 4; r++) {
                float pe = exp2_fast(fmaf(s[tt][r], 1.442695041f, -11.54156033f));
                ls += pe;
                pf[tt][r] = (short)(__float_as_uint(pe) >> 16);
            }
        }
        lsum += ls;
#pragma unroll
        for (int tt = 0; tt < 4; tt++)
            o = mfma16(pf[tt], vf[tt], o);
    };

    issue_pair(p0, base); issue_pair(p1, base + 1);
    issue_kv(k0, v0, base); issue_kv(k1, v1, base + 1);

    for (int kt = base; kt < kend; kt += 2) {
        step(p0, k0, v0);
        if (kt + 2 < kend) { issue_pair(p0, kt + 2); issue_kv(k0, v0, kt + 2); }
        step(p1, k1, v1);
        if (kt + 3 < kend) { issue_pair(p1, kt + 3); issue_kv(k1, v1, kt + 3); }
    }

    lsum += __shfl_xor(lsum, 16);
    lsum += __shfl_xor(lsum, 32);
    if (l < 16) lsumL[w * 16 + l] = lsum;

    float* oLw = PS;
#pragma unroll
    for (int r = 0; r < 4; r++)
        oLw[(4 * g + r) * 17 + q] = o[r];
    __syncthreads();

    const int row = t >> 4, d = t & 15;
    float osum = 0.f, lt = 0.f;
#pragma unroll
    for (int ww = 0; ww < 4; ww++) {
        osum += SM[ww * 1088 + row * 17 + d];
        lt   += lsumL[ww * 16 + row];
    }
    size_t idx = ((size_t)b * 2048 + q0 + row) * 128 + h * 16 + d;
    ao[idx] = f2bf(osum * (1.0f / lt) * bf2f(gate[idx]));
}

// ---------------- K3: fused post-attention + transition, fragment-major weights ----------------
__global__ __launch_bounds__(512)
void post_trans(const u16* __restrict__ aob, const float* __restrict__ scq,
                const float* __restrict__ x_q,
                const float* __restrict__ azi_bc, const float* __restrict__ t_cond_w,
                const float* __restrict__ t_scale_b, const float* __restrict__ t_azi_bc,
                const u16* __restrict__ wT, float* __restrict__ out)
{
    __shared__ u16 aoL[16][132];
    __shared__ u16 scL[16][132];
    __shared__ u16 cnL[16][132];
    __shared__ u16 ynL[16][132];
    __shared__ u16 aaL[16][132];
    __shared__ float yL[16][132];
    __shared__ u16 hL[16][520];
    const int rowblk = blockIdx.x * 16;
    const int t = threadIdx.x, lane = t & 63, w = t >> 6;   // 8 waves
    const int j15 = lane & 15, g = lane >> 4;
    const int c = w * 16 + j15;

    {   // P0: 32 lanes/row, 4 elems/lane; stage ao(bf16)/sc/x_q, LN(scq)*t_cond_w
        const int r = t >> 5, p = t & 31;
        const size_t base = (size_t)(rowblk + r) * 128 + p * 4;
        uint2 araw = *(const uint2*)(aob + base);
        float cv[4], xv[4];
        *(float4*)&cv[0] = *(const float4*)(scq + base);
        *(float4*)&xv[0] = *(const float4*)(x_q + base);
        float sc = 0, scc = 0;
#pragma unroll
        for (int u = 0; u < 4; u++) { sc += cv[u]; scc += cv[u] * cv[u]; }
#pragma unroll
        for (int off = 1; off < 32; off <<= 1) {
            sc += __shfl_xor(sc, off); scc += __shfl_xor(scc, off);
        }
        const float inv = 1.0f / 128.0f;
        float mc = sc * inv, vc = scc * inv - mc * mc, rc = rsqrtf(vc + 1e-5f);
        *(uint2*)&aoL[r][p * 4] = araw;    // already bf16
#pragma unroll
        for (int u = 0; u < 4; u++) {
            int e = p * 4 + u;
            scL[r][e] = f2bf(cv[u]);
            cnL[r][e] = f2bf((cv[u] - mc) * rc * t_cond_w[e]);
            yL[r][e]  = xv[u];
        }
    }
    __syncthreads();

    // Merged GEMM-A+B: 5 streams, 1 ct per wave
    f32x4 at_ = (f32x4)0.f, ac_ = (f32x4)0.f;
    f32x4 s_  = (f32x4)0.f, b_  = (f32x4)0.f, gg_ = (f32x4)0.f;
    {
        const u16* Bt = wT + WT_AZIT;
        const u16* Bc = wT + WT_AZIC;
        const u16* Bs = wT + WT_TS;
        const u16* Bb = wT + WT_TB;
        const u16* Bg = wT + WT_TAZIC;
#pragma unroll
        for (int kk = 0; kk < 8; kk++) {
            size_t fo = ((size_t)(w * 8 + kk) * 64 + lane) * 4;
            bf16x4 a_ao = *(bf16x4*)&aoL[j15][kk * 16 + 4 * g];
            bf16x4 a_sc = *(bf16x4*)&scL[j15][kk * 16 + 4 * g];
            bf16x4 a_cn = *(bf16x4*)&cnL[j15][kk * 16 + 4 * g];
            bf16x4 bt  = *(const bf16x4*)(Bt + fo);
            bf16x4 bc2 = *(const bf16x4*)(Bc + fo);
            bf16x4 bs  = *(const bf16x4*)(Bs + fo);
            bf16x4 bb  = *(const bf16x4*)(Bb + fo);
            bf16x4 bg  = *(const bf16x4*)(Bg + fo);
            at_ = mfma16(a_ao, bt,  at_);
            ac_ = mfma16(a_sc, bc2, ac_);
            s_  = mfma16(a_cn, bs,  s_);
            b_  = mfma16(a_cn, bb,  b_);
            gg_ = mfma16(a_sc, bg,  gg_);
        }
    }
    {
        float bc0 = azi_bc[c];
#pragma unroll
        for (int reg = 0; reg < 4; reg++) {
            int nl = 4 * g + reg;
            yL[nl][c] = yL[nl][c] + sigmoidf_(ac_[reg] + bc0) * at_[reg];
        }
    }
    __syncthreads();

    {   // LN(y)
        const int r = t >> 5, p = t & 31;
        float yv[4];
        *(float4*)&yv[0] = *(float4*)&yL[r][p * 4];
        float sy = 0, syy = 0;
#pragma unroll
        for (int u = 0; u < 4; u++) { sy += yv[u]; syy += yv[u] * yv[u]; }
#pragma unroll
        for (int off = 1; off < 32; off <<= 1) {
            sy += __shfl_xor(sy, off); syy += __shfl_xor(syy, off);
        }
        const float inv = 1.0f / 128.0f;
        float my = sy * inv, vy = syy * inv - my * my, ry = rsqrtf(vy + 1e-5f);
#pragma unroll
        for (int u = 0; u < 4; u++)
            ynL[r][p * 4 + u] = f2bf((yv[u] - my) * ry);
    }
    __syncthreads();

    f32x4 tg_;
    {
        float sb = t_scale_b[c], tb = t_azi_bc[c];
#pragma unroll
        for (int reg = 0; reg < 4; reg++) {
            int nl = 4 * g + reg;
            aaL[nl][c] = f2bf(sigmoidf_(s_[reg] + sb) * bf2f(ynL[nl][c]) + b_[reg]);
            tg_[reg] = sigmoidf_(gg_[reg] + tb);
        }
    }
    __syncthreads();

    // GEMM-C
    {
        const u16* G1 = wT + WT_GLU1;
        const u16* G2 = wT + WT_GLU2;
        f32x4 h1_[4], h2_[4];
#pragma unroll
        for (int i = 0; i < 4; i++) { h1_[i] = (f32x4)0.f; h2_[i] = (f32x4)0.f; }
#pragma unroll
        for (int kk = 0; kk < 8; kk++) {
            bf16x4 a = *(bf16x4*)&aaL[j15][kk * 16 + 4 * g];
#pragma unroll
            for (int u = 0; u < 4; u++) {
                size_t fo = ((size_t)((w * 4 + u) * 8 + kk) * 64 + lane) * 4;
                bf16x4 b1 = *(const bf16x4*)(G1 + fo);
                bf16x4 b2 = *(const bf16x4*)(G2 + fo);
                h1_[u] = mfma16(a, b1, h1_[u]);
                h2_[u] = mfma16(a, b2, h2_[u]);
            }
        }
#pragma unroll
        for (int u = 0; u < 4; u++) {
            int cc = (w * 4 + u) * 16 + j15;
#pragma unroll
            for (int reg = 0; reg < 4; reg++) {
                int nl = 4 * g + reg;
                float hv1 = h1_[u][reg];
                hL[nl][cc] = f2bf(hv1 * sigmoidf_(hv1) * h2_[u][reg]);
            }
        }
    }
    __syncthreads();

    // GEMM-D
    f32x4 td[4];
#pragma unroll
    for (int i = 0; i < 4; i++) td[i] = (f32x4)0.f;
    {
        const u16* W4 = wT + WT_TAZIT;
#pragma unroll
        for (int kk = 0; kk < 32; kk++) {
            bf16x4 a = *(bf16x4*)&hL[j15][kk * 16 + 4 * g];
            bf16x4 b = *(const bf16x4*)(W4 + ((size_t)(w * 32 + kk) * 64 + lane) * 4);
            td[kk & 3] = mfma16(a, b, td[kk & 3]);
        }
    }
#pragma unroll
    for (int reg = 0; reg < 4; reg++) {
        int nl = 4 * g + reg;
        size_t gi = (size_t)(rowblk + nl) * 128 + c;
        out[gi] = yL[nl][c] + tg_[reg] * (td[0][reg] + td[1][reg] + td[2][reg] + td[3][reg]);
    }
}

extern "C" void kernel_launch(void* const* d_in, const int* in_sizes, int n_in,
                              void* d_out, int out_size, void* d_ws, size_t ws_size,
                              hipStream_t stream)
{
    (void)in_sizes; (void)n_in; (void)out_size; (void)ws_size;
    const float* x_q      = (const float*)d_in[0];
    const float* x_k      = (const float*)d_in[1];
    const float* pair     = (const float*)d_in[4];
    const float* scq      = (const float*)d_in[5];
    const float* sck      = (const float*)d_in[6];
    const float* q_cond_w = (const float*)d_in[7];
    const float* q_scale_w= (const float*)d_in[8];
    const float* q_scale_b= (const float*)d_in[9];
    const float* q_bias_w = (const float*)d_in[10];
    const float* k_cond_w = (const float*)d_in[11];
    const float* k_scale_w= (const float*)d_in[12];
    const float* k_scale_b= (const float*)d_in[13];
    const float* k_bias_w = (const float*)d_in[14];
    const float* wq       = (const float*)d_in[15];
    const float* bq       = (const float*)d_in[16];
    const float* wk       = (const float*)d_in[17];
    const float* wv       = (const float*)d_in[18];
    const float* wg       = (const float*)d_in[19];
    const float* azi_wt   = (const float*)d_in[20];
    const float* azi_wc   = (const float*)d_in[21];
    const float* azi_bc   = (const float*)d_in[22];
    const float* t_cond_w = (const float*)d_in[23];
    const float* t_scale_w= (const float*)d_in[24];
    const float* t_scale_b= (const float*)d_in[25];
    const float* t_bias_w = (const float*)d_in[26];
    const float* glu1     = (const float*)d_in[27];
    const float* glu2     = (const float*)d_in[28];
    const float* t_azi_wt = (const float*)d_in[29];
    const float* t_azi_wc = (const float*)d_in[30];
    const float* t_azi_bc = (const float*)d_in[31];

    float* out = (float*)d_out;
    u16* qs   = (u16*)d_ws;                  // bf16 [16][2048][16]   1MB
    u16* ks   = qs + 524288;                 // 1MB
    u16* vt   = ks + 524288;                 // bf16 [16][16][2048]   1MB
    u16* gate = vt + 524288;                 // bf16 [4096][128]      1MB
    u16* aob  = gate + 524288;               // bf16 [4096][128]      1MB
    u16* wT   = aob + 524288;                // bf16 weights (fragment-major) 0.8MB

    prep_kernel<<<152, 256, 0, stream>>>(
        q_scale_w, q_bias_w, wq, wg, k_scale_w, k_bias_w, wk, wv,
        azi_wt, azi_wc, t_scale_w, t_bias_w, t_azi_wc, glu1, glu2, t_azi_wt, wT);
    adaln_mfma<<<256, 512, 0, stream>>>(
        x_q, scq, x_k, sck, q_cond_w, q_scale_b, bq, k_cond_w, k_scale_b,
        wT, qs, ks, vt, gate);
    attn_kernel<<<B_ * H_ * (N_ / 16), 256, 0, stream>>>(qs, ks, vt, pair, gate, aob);
    post_trans<<<NROW / 16, 512, 0, stream>>>(
        aob, scq, x_q, azi_bc, t_cond_w, t_scale_b, t_azi_bc, wT, out);
}

// Round 15
// 86.043 us; speedup vs baseline: 1.0684x; 1.0063x over previous
//
#include <hip/hip_runtime.h>
#include <cmath>

#define B_ 2
#define N_ 2048
#define C_ 128
#define H_ 8
#define D_ 16
#define CI_ 512
#define NROW 4096

typedef float f32x4 __attribute__((ext_vector_type(4)));
typedef short bf16x4 __attribute__((ext_vector_type(4)));
typedef unsigned short u16;

__device__ __forceinline__ float sigmoidf_(float x) {
    return 1.0f / (1.0f + __expf(-x));
}

__device__ __forceinline__ u16 f2bf(float x) {
    union { float f; unsigned int u; } v; v.f = x;
    unsigned int r = v.u + 0x7fffu + ((v.u >> 16) & 1u);
    return (u16)(r >> 16);
}

__device__ __forceinline__ float bf2f(u16 b) {
    union { unsigned int u; float f; } v; v.u = ((unsigned int)b) << 16;
    return v.f;
}

__device__ __forceinline__ float exp2_fast(float x) {
#if __has_builtin(__builtin_amdgcn_exp2f)
    return __builtin_amdgcn_exp2f(x);
#else
    return __expf(x * 0.6931471806f);
#endif
}

__device__ __forceinline__ f32x4 mfma16(bf16x4 a, bf16x4 b, f32x4 c) {
#if __has_builtin(__builtin_amdgcn_mfma_f32_16x16x16bf16_1k)
    return __builtin_amdgcn_mfma_f32_16x16x16bf16_1k(a, b, c, 0, 0, 0);
#else
    asm("v_mfma_f32_16x16x16_bf16 %0, %1, %2, %0\n\ts_nop 7\n\ts_nop 3"
        : "+v"(c) : "v"(a), "v"(b));
    return c;
#endif
}

// Weight regions (u16 elements). FRAGMENT-MAJOR layout:
// wF[((ct*KK + kk)*64 + lane)*4 + e] = W^T[ct*16 + (lane&15)][kk*16 + 4*(lane>>4) + e]
#define WT_QS    0
#define WT_QB    16384
#define WT_WQ    32768
#define WT_WG    49152
#define WT_KS    65536
#define WT_KB    81920
#define WT_WK    98304
#define WT_WV    114688
#define WT_AZIT  131072
#define WT_AZIC  147456
#define WT_TS    163840
#define WT_TB    180224
#define WT_TAZIC 196608
#define WT_GLU1  212992
#define WT_GLU2  278528
#define WT_TAZIT 344064
#define WT_TOTAL 409600

// ---------------- K0: convert weights to bf16 fragment-major tiles ----------------
__global__ __launch_bounds__(256)
void prep_kernel(const float* qs_w, const float* qb_w, const float* wq, const float* wg,
                 const float* ks_w, const float* kb_w, const float* wk, const float* wv,
                 const float* azi_wt, const float* azi_wc, const float* ts_w, const float* tb_w,
                 const float* tazi_wc, const float* glu1, const float* glu2, const float* tazi_wt,
                 u16* wT)
{
    __shared__ float lds[16 * 512];
    const int blk = blockIdx.x;
    const float* src; int width, kk, KK; u16* dst;
    if (blk < 104) {
        int m = blk >> 3; kk = blk & 7;
        const float* srcs[13] = {qs_w, qb_w, wq, wg, ks_w, kb_w, wk, wv,
                                 azi_wt, azi_wc, ts_w, tb_w, tazi_wc};
        src = srcs[m]; width = 128; KK = 8;
        dst = wT + m * 16384;
    } else if (blk < 112) {
        kk = blk - 104; src = glu1; width = 512; KK = 8; dst = wT + WT_GLU1;
    } else if (blk < 120) {
        kk = blk - 112; src = glu2; width = 512; KK = 8; dst = wT + WT_GLU2;
    } else {
        kk = blk - 120; src = tazi_wt; width = 128; KK = 32; dst = wT + WT_TAZIT;
    }
    const int t = threadIdx.x;
    const int w4 = width >> 2;
    for (int idx = t; idx < 16 * w4; idx += 256) {
        int r = idx / w4, c4 = (idx % w4) * 4;
        *(float4*)&lds[r * width + c4] =
            *(const float4*)(src + (size_t)(kk * 16 + r) * width + c4);
    }
    __syncthreads();
    const int CT = width >> 4;
    for (int it = t; it < CT * 64; it += 256) {
        int ct = it >> 6, l = it & 63;
        int j15 = l & 15, gg = l >> 4;
        u16 e0 = f2bf(lds[(4 * gg + 0) * width + ct * 16 + j15]);
        u16 e1 = f2bf(lds[(4 * gg + 1) * width + ct * 16 + j15]);
        u16 e2 = f2bf(lds[(4 * gg + 2) * width + ct * 16 + j15]);
        u16 e3 = f2bf(lds[(4 * gg + 3) * width + ct * 16 + j15]);
        uint2 pk;
        pk.x = (unsigned)e0 | ((unsigned)e1 << 16);
        pk.y = (unsigned)e2 | ((unsigned)e3 << 16);
        *(uint2*)(dst + ((size_t)(ct * KK + kk) * 64 + l) * 4) = pk;
    }
}

// ---------------- K1: fused AdaLN + projections, 32 rows/block, 512 thr ----------------
__global__ __launch_bounds__(512)
void adaln_mfma(const float* __restrict__ x_q, const float* __restrict__ scq,
                const float* __restrict__ x_k, const float* __restrict__ sck,
                const float* __restrict__ q_cond_w, const float* __restrict__ q_scale_b,
                const float* __restrict__ bq,
                const float* __restrict__ k_cond_w, const float* __restrict__ k_scale_b,
                const u16* __restrict__ wT,
                u16* __restrict__ qs, u16* __restrict__ ks, u16* __restrict__ vt,
                u16* __restrict__ gate)
{
    __shared__ u16 xn[32][132];
    __shared__ u16 cn[32][132];
    __shared__ u16 xq[32][132];
    __shared__ u16 vls[128][40];
    const int bi = blockIdx.x;            // 256 blocks
    const int qside = (bi < 128) ? 1 : 0;
    const int rowblk = (bi & 127) * 32;
    const float* xin = qside ? x_q : x_k;
    const float* cin = qside ? scq : sck;
    const float* cw  = qside ? q_cond_w : k_cond_w;
    const float* slb = qside ? q_scale_b : k_scale_b;
    const u16* Wsc = wT + (qside ? WT_QS : WT_KS);
    const u16* Wbi = wT + (qside ? WT_QB : WT_KB);
    const u16* W1  = wT + (qside ? WT_WQ : WT_WK);
    const u16* W2  = wT + (qside ? WT_WG : WT_WV);

    const int t = threadIdx.x;
    {   // LN: 16 lanes/row, 8 elems/lane, 32 rows
        const int r = t >> 4, p = t & 15;
        const size_t base = (size_t)(rowblk + r) * 128 + p * 8;
        float xv[8], cv[8];
        *(float4*)&xv[0] = *(const float4*)(xin + base);
        *(float4*)&xv[4] = *(const float4*)(xin + base + 4);
        *(float4*)&cv[0] = *(const float4*)(cin + base);
        *(float4*)&cv[4] = *(const float4*)(cin + base + 4);
        float sx = 0, sxx = 0, sc = 0, scc = 0;
#pragma unroll
        for (int u = 0; u < 8; u++) {
            sx += xv[u]; sxx += xv[u] * xv[u];
            sc += cv[u]; scc += cv[u] * cv[u];
        }
#pragma unroll
        for (int off = 1; off < 16; off <<= 1) {
            sx += __shfl_xor(sx, off); sxx += __shfl_xor(sxx, off);
            sc += __shfl_xor(sc, off); scc += __shfl_xor(scc, off);
        }
        const float inv = 1.0f / 128.0f;
        float mx = sx * inv, vx = sxx * inv - mx * mx, rx = rsqrtf(vx + 1e-5f);
        float mc = sc * inv, vc = scc * inv - mc * mc, rc = rsqrtf(vc + 1e-5f);
#pragma unroll
        for (int u4 = 0; u4 < 2; u4++) {
            bf16x4 xw, cwv;
#pragma unroll
            for (int i = 0; i < 4; i++) {
                int e = p * 8 + u4 * 4 + i;
                xw[i]  = (short)f2bf((xv[u4 * 4 + i] - mx) * rx);
                cwv[i] = (short)f2bf((cv[u4 * 4 + i] - mc) * rc * cw[e]);
            }
            *(bf16x4*)&xn[r][p * 8 + u4 * 4] = xw;
            *(bf16x4*)&cn[r][p * 8 + u4 * 4] = cwv;
        }
    }
    __syncthreads();

    const int lane = t & 63, w = t >> 6;       // 8 waves, ct = w
    const int j15 = lane & 15, g = lane >> 4;
    const int c = w * 16 + j15;

    // GEMM1: adaptive scale + bias, 2 row-halves per wave
    f32x4 as0 = (f32x4)0.f, as1 = (f32x4)0.f, ab0 = (f32x4)0.f, ab1 = (f32x4)0.f;
#pragma unroll
    for (int kk = 0; kk < 8; kk++) {
        bf16x4 a0 = *(bf16x4*)&cn[j15][kk * 16 + 4 * g];
        bf16x4 a1 = *(bf16x4*)&cn[16 + j15][kk * 16 + 4 * g];
        bf16x4 bs = *(const bf16x4*)(Wsc + ((size_t)(w * 8 + kk) * 64 + lane) * 4);
        bf16x4 bb = *(const bf16x4*)(Wbi + ((size_t)(w * 8 + kk) * 64 + lane) * 4);
        as0 = mfma16(a0, bs, as0);  as1 = mfma16(a1, bs, as1);
        ab0 = mfma16(a0, bb, ab0);  ab1 = mfma16(a1, bb, ab1);
    }
    {
        float sb = slb[c];
#pragma unroll
        for (int reg = 0; reg < 4; reg++) {
            int nl = 4 * g + reg;
            xq[nl][c]      = f2bf(sigmoidf_(as0[reg] + sb) * bf2f(xn[nl][c]) + ab0[reg]);
            xq[16 + nl][c] = f2bf(sigmoidf_(as1[reg] + sb) * bf2f(xn[16 + nl][c]) + ab1[reg]);
        }
    }
    __syncthreads();

    // GEMM2: w1 (q/k), w2 (gate/v)
    f32x4 o10 = (f32x4)0.f, o11 = (f32x4)0.f, o20 = (f32x4)0.f, o21 = (f32x4)0.f;
#pragma unroll
    for (int kk = 0; kk < 8; kk++) {
        bf16x4 a0 = *(bf16x4*)&xq[j15][kk * 16 + 4 * g];
        bf16x4 a1 = *(bf16x4*)&xq[16 + j15][kk * 16 + 4 * g];
        bf16x4 b1 = *(const bf16x4*)(W1 + ((size_t)(w * 8 + kk) * 64 + lane) * 4);
        bf16x4 b2 = *(const bf16x4*)(W2 + ((size_t)(w * 8 + kk) * 64 + lane) * 4);
        o10 = mfma16(a0, b1, o10);  o11 = mfma16(a1, b1, o11);
        o20 = mfma16(a0, b2, o20);  o21 = mfma16(a1, b2, o21);
    }
    const int b = rowblk >> 11, n0 = rowblk & 2047;
    if (qside) {
        float bqv = bq[c];
#pragma unroll
        for (int reg = 0; reg < 4; reg++) {
            int n_a = n0 + 4 * g + reg, n_b = n_a + 16;
            qs[(((size_t)b * 8 + w) * 2048 + n_a) * 16 + j15] = f2bf((o10[reg] + bqv) * 0.25f);
            qs[(((size_t)b * 8 + w) * 2048 + n_b) * 16 + j15] = f2bf((o11[reg] + bqv) * 0.25f);
            gate[((size_t)b * 2048 + n_a) * 128 + c] = f2bf(sigmoidf_(o20[reg]));
            gate[((size_t)b * 2048 + n_b) * 128 + c] = f2bf(sigmoidf_(o21[reg]));
        }
    } else {
#pragma unroll
        for (int reg = 0; reg < 4; reg++) {
            int n_a = n0 + 4 * g + reg, n_b = n_a + 16;
            ks[(((size_t)b * 8 + w) * 2048 + n_a) * 16 + j15] = f2bf(o10[reg]);
            ks[(((size_t)b * 8 + w) * 2048 + n_b) * 16 + j15] = f2bf(o11[reg]);
            vls[c][4 * g + reg]      = f2bf(o20[reg]);
            vls[c][16 + 4 * g + reg] = f2bf(o21[reg]);
        }
        __syncthreads();
        const int cc = t & 127, qtr = t >> 7;   // qtr 0..3 -> 8 n each
        const int h = cc >> 4, d = cc & 15;
        unsigned pk[4];
#pragma unroll
        for (int u2 = 0; u2 < 4; u2++)
            pk[u2] = (unsigned)vls[cc][qtr * 8 + 2 * u2] |
                     ((unsigned)vls[cc][qtr * 8 + 2 * u2 + 1] << 16);
        u16* vp = vt + ((size_t)(b * 8 + h) * 16 + d) * 2048 + n0 + qtr * 8;
        *(uint4*)vp = *(uint4*)pk;
    }
}

// ---------------- K2: MFMA attention, 32 q-rows/block, 8 waves (2 halves x 4-way split) ----------------
__global__ __launch_bounds__(512, 4)
void attn_kernel(const u16* __restrict__ qg, const u16* __restrict__ kg,
                 const u16* __restrict__ vtg, const float* __restrict__ pair,
                 const u16* __restrict__ gate, u16* __restrict__ ao)
{
    __shared__ float SM[8 * 1088 + 128];   // 8x PS[16][68] (oL overlays) + lsum[8][16]
    const int t = threadIdx.x;
    const int l = t & 63, w = t >> 6;      // 8 waves
    const int g = l >> 4, q = l & 15;
    const int ws = w & 3, qh = w >> 2;     // key-split idx, q-half
    // XCD-aware bijective swizzle over 1024 blocks
    const int wid = (blockIdx.x & 7) * 128 + (blockIdx.x >> 3);
    const int qt = wid & 63;
    const int bh = wid >> 6;
    const int b = bh >> 3, h = bh & 7;
    const int q0 = qt * 32 + qh * 16;
    float* PS = SM + w * 1088;
    float* lsumL = SM + 8 * 1088;          // [8][16]

    const u16* qb = qg + ((size_t)bh * 2048 + q0 + q) * 16 + 4 * g;
    const u16* kb = kg + ((size_t)bh * 2048 + q) * 16 + 4 * g;
    const u16* vb = vtg + ((size_t)bh * 16 + q) * 2048 + 4 * g;
    const float* pb = pair + (size_t)bh * N_ * N_ + (size_t)(q0 + g) * N_ + q * 4;

    bf16x4 qf = *(const bf16x4*)qb;

    f32x4 o = {0.f, 0.f, 0.f, 0.f};
    float lsum = 0.f;
    const int base = ws * 8, kend = base + 8;

    f32x4 p0[4], p1[4];
    bf16x4 k0[4], v0[4], k1[4], v1[4];

    auto issue_pair = [&](f32x4 (&pr)[4], int kt) {
        const float* pt = pb + kt * 64;
#pragma unroll
        for (int i = 0; i < 4; i++)
            pr[i] = *(const f32x4*)(pt + (size_t)(4 * i) * N_);
    };
    auto issue_kv = [&](bf16x4 (&kf)[4], bf16x4 (&vf)[4], int kt) {
#pragma unroll
        for (int tt = 0; tt < 4; tt++) {
            kf[tt] = *(const bf16x4*)(kb + (size_t)(kt * 64 + tt * 16) * 16);
            vf[tt] = *(const bf16x4*)(vb + kt * 64 + tt * 16);
        }
    };
    auto step = [&](f32x4 (&pr)[4], bf16x4 (&kf)[4], bf16x4 (&vf)[4]) {
#pragma unroll
        for (int i = 0; i < 4; i++)
            *(f32x4*)&PS[(g + 4 * i) * 68 + q * 4] = pr[i];
        asm volatile("s_waitcnt lgkmcnt(0)" ::: "memory");
        __builtin_amdgcn_sched_barrier(0);
        f32x4 s[4];
#pragma unroll
        for (int tt = 0; tt < 4; tt++) {
            f32x4 c = *(const f32x4*)&PS[q * 68 + tt * 16 + 4 * g];
            s[tt] = mfma16(kf[tt], qf, c);       // S^T: row=key(4g+reg), col=q
        }
        bf16x4 pf[4];
        float ls = 0.f;
#pragma unroll
        for (int tt = 0; tt < 4; tt++) {
#pragma unroll
            for (int r = 0; r < 4; r++) {
                float pe = exp2_fast(fmaf(s[tt][r], 1.442695041f, -11.54156033f));
                ls += pe;
                pf[tt][r] = (short)(__float_as_uint(pe) >> 16);
            }
        }
        lsum += ls;
#pragma unroll
        for (int tt = 0; tt < 4; tt++)
            o = mfma16(pf[tt], vf[tt], o);       // O: row=q(4g+reg), col=d(q lane)
    };

    issue_pair(p0, base); issue_pair(p1, base + 1);
    issue_kv(k0, v0, base); issue_kv(k1, v1, base + 1);

    for (int kt = base; kt < kend; kt += 2) {
        step(p0, k0, v0);
        if (kt + 2 < kend) { issue_pair(p0, kt + 2); issue_kv(k0, v0, kt + 2); }
        step(p1, k1, v1);
        if (kt + 3 < kend) { issue_pair(p1, kt + 3); issue_kv(k1, v1, kt + 3); }
    }

    // lsum: full sum for q-row q over this wave's keys
    lsum += __shfl_xor(lsum, 16);
    lsum += __shfl_xor(lsum, 32);
    if (l < 16) lsumL[w * 16 + l] = lsum;

    // stash o partials in this wave's (dead) PS region: [16 rows][17]
    float* oLw = PS;
#pragma unroll
    for (int r = 0; r < 4; r++)
        oLw[(4 * g + r) * 17 + q] = o[r];
    __syncthreads();

    // merge: 512 threads = 32 rows x 16 dims; half rh merges waves rh*4..rh*4+3
    const int row = t >> 4, d = t & 15;
    const int rh = row >> 4, rr = row & 15;
    float osum = 0.f, lt = 0.f;
#pragma unroll
    for (int ww = 0; ww < 4; ww++) {
        osum += SM[(rh * 4 + ww) * 1088 + rr * 17 + d];
        lt   += lsumL[(rh * 4 + ww) * 16 + rr];
    }
    size_t idx = ((size_t)b * 2048 + qt * 32 + row) * 128 + h * 16 + d;
    ao[idx] = f2bf(osum * (1.0f / lt) * bf2f(gate[idx]));
}

// ---------------- K3: fused post-attention + transition, fragment-major weights ----------------
__global__ __launch_bounds__(512)
void post_trans(const u16* __restrict__ aob, const float* __restrict__ scq,
                const float* __restrict__ x_q,
                const float* __restrict__ azi_bc, const float* __restrict__ t_cond_w,
                const float* __restrict__ t_scale_b, const float* __restrict__ t_azi_bc,
                const u16* __restrict__ wT, float* __restrict__ out)
{
    __shared__ u16 aoL[16][132];
    __shared__ u16 scL[16][132];
    __shared__ u16 cnL[16][132];
    __shared__ u16 ynL[16][132];
    __shared__ u16 aaL[16][132];
    __shared__ float yL[16][132];
    __shared__ u16 hL[16][520];
    const int rowblk = blockIdx.x * 16;
    const int t = threadIdx.x, lane = t & 63, w = t >> 6;   // 8 waves
    const int j15 = lane & 15, g = lane >> 4;
    const int c = w * 16 + j15;

    {   // P0: 32 lanes/row, 4 elems/lane; stage ao(bf16)/sc/x_q, LN(scq)*t_cond_w
        const int r = t >> 5, p = t & 31;
        const size_t base = (size_t)(rowblk + r) * 128 + p * 4;
        uint2 araw = *(const uint2*)(aob + base);
        float cv[4], xv[4];
        *(float4*)&cv[0] = *(const float4*)(scq + base);
        *(float4*)&xv[0] = *(const float4*)(x_q + base);
        float sc = 0, scc = 0;
#pragma unroll
        for (int u = 0; u < 4; u++) { sc += cv[u]; scc += cv[u] * cv[u]; }
#pragma unroll
        for (int off = 1; off < 32; off <<= 1) {
            sc += __shfl_xor(sc, off); scc += __shfl_xor(scc, off);
        }
        const float inv = 1.0f / 128.0f;
        float mc = sc * inv, vc = scc * inv - mc * mc, rc = rsqrtf(vc + 1e-5f);
        *(uint2*)&aoL[r][p * 4] = araw;    // already bf16
#pragma unroll
        for (int u = 0; u < 4; u++) {
            int e = p * 4 + u;
            scL[r][e] = f2bf(cv[u]);
            cnL[r][e] = f2bf((cv[u] - mc) * rc * t_cond_w[e]);
            yL[r][e]  = xv[u];
        }
    }
    __syncthreads();

    // Merged GEMM-A+B: 5 streams, 1 ct per wave
    f32x4 at_ = (f32x4)0.f, ac_ = (f32x4)0.f;
    f32x4 s_  = (f32x4)0.f, b_  = (f32x4)0.f, gg_ = (f32x4)0.f;
    {
        const u16* Bt = wT + WT_AZIT;
        const u16* Bc = wT + WT_AZIC;
        const u16* Bs = wT + WT_TS;
        const u16* Bb = wT + WT_TB;
        const u16* Bg = wT + WT_TAZIC;
#pragma unroll
        for (int kk = 0; kk < 8; kk++) {
            size_t fo = ((size_t)(w * 8 + kk) * 64 + lane) * 4;
            bf16x4 a_ao = *(bf16x4*)&aoL[j15][kk * 16 + 4 * g];
            bf16x4 a_sc = *(bf16x4*)&scL[j15][kk * 16 + 4 * g];
            bf16x4 a_cn = *(bf16x4*)&cnL[j15][kk * 16 + 4 * g];
            bf16x4 bt  = *(const bf16x4*)(Bt + fo);
            bf16x4 bc2 = *(const bf16x4*)(Bc + fo);
            bf16x4 bs  = *(const bf16x4*)(Bs + fo);
            bf16x4 bb  = *(const bf16x4*)(Bb + fo);
            bf16x4 bg  = *(const bf16x4*)(Bg + fo);
            at_ = mfma16(a_ao, bt,  at_);
            ac_ = mfma16(a_sc, bc2, ac_);
            s_  = mfma16(a_cn, bs,  s_);
            b_  = mfma16(a_cn, bb,  b_);
            gg_ = mfma16(a_sc, bg,  gg_);
        }
    }
    {
        float bc0 = azi_bc[c];
#pragma unroll
        for (int reg = 0; reg < 4; reg++) {
            int nl = 4 * g + reg;
            yL[nl][c] = yL[nl][c] + sigmoidf_(ac_[reg] + bc0) * at_[reg];
        }
    }
    __syncthreads();

    {   // LN(y)
        const int r = t >> 5, p = t & 31;
        float yv[4];
        *(float4*)&yv[0] = *(float4*)&yL[r][p * 4];
        float sy = 0, syy = 0;
#pragma unroll
        for (int u = 0; u < 4; u++) { sy += yv[u]; syy += yv[u] * yv[u]; }
#pragma unroll
        for (int off = 1; off < 32; off <<= 1) {
            sy += __shfl_xor(sy, off); syy += __shfl_xor(syy, off);
        }
        const float inv = 1.0f / 128.0f;
        float my = sy * inv, vy = syy * inv - my * my, ry = rsqrtf(vy + 1e-5f);
#pragma unroll
        for (int u = 0; u < 4; u++)
            ynL[r][p * 4 + u] = f2bf((yv[u] - my) * ry);
    }
    __syncthreads();

    f32x4 tg_;
    {
        float sb = t_scale_b[c], tb = t_azi_bc[c];
#pragma unroll
        for (int reg = 0; reg < 4; reg++) {
            int nl = 4 * g + reg;
            aaL[nl][c] = f2bf(sigmoidf_(s_[reg] + sb) * bf2f(ynL[nl][c]) + b_[reg]);
            tg_[reg] = sigmoidf_(gg_[reg] + tb);
        }
    }
    __syncthreads();

    // GEMM-C
    {
        const u16* G1 = wT + WT_GLU1;
        const u16* G2 = wT + WT_GLU2;
        f32x4 h1_[4], h2_[4];
#pragma unroll
        for (int i = 0; i < 4; i++) { h1_[i] = (f32x4)0.f; h2_[i] = (f32x4)0.f; }
#pragma unroll
        for (int kk = 0; kk < 8; kk++) {
            bf16x4 a = *(bf16x4*)&aaL[j15][kk * 16 + 4 * g];
#pragma unroll
            for (int u = 0; u < 4; u++) {
                size_t fo = ((size_t)((w * 4 + u) * 8 + kk) * 64 + lane) * 4;
                bf16x4 b1 = *(const bf16x4*)(G1 + fo);
                bf16x4 b2 = *(const bf16x4*)(G2 + fo);
                h1_[u] = mfma16(a, b1, h1_[u]);
                h2_[u] = mfma16(a, b2, h2_[u]);
            }
        }
#pragma unroll
        for (int u = 0; u < 4; u++) {
            int cc = (w * 4 + u) * 16 + j15;
#pragma unroll
            for (int reg = 0; reg < 4; reg++) {
                int nl = 4 * g + reg;
                float hv1 = h1_[u][reg];
                hL[nl][cc] = f2bf(hv1 * sigmoidf_(hv1) * h2_[u][reg]);
            }
        }
    }
    __syncthreads();

    // GEMM-D
    f32x4 td[4];
#pragma unroll
    for (int i = 0; i < 4; i++) td[i] = (f32x4)0.f;
    {
        const u16* W4 = wT + WT_TAZIT;
#pragma unroll
        for (int kk = 0; kk < 32; kk++) {
            bf16x4 a = *(bf16x4*)&hL[j15][kk * 16 + 4 * g];
            bf16x4 b = *(const bf16x4*)(W4 + ((size_t)(w * 32 + kk) * 64 + lane) * 4);
            td[kk & 3] = mfma16(a, b, td[kk & 3]);
        }
    }
#pragma unroll
    for (int reg = 0; reg < 4; reg++) {
        int nl = 4 * g + reg;
        size_t gi = (size_t)(rowblk + nl) * 128 + c;
        out[gi] = yL[nl][c] + tg_[reg] * (td[0][reg] + td[1][reg] + td[2][reg] + td[3][reg]);
    }
}

extern "C" void kernel_launch(void* const* d_in, const int* in_sizes, int n_in,
                              void* d_out, int out_size, void* d_ws, size_t ws_size,
                              hipStream_t stream)
{
    (void)in_sizes; (void)n_in; (void)out_size; (void)ws_size;
    const float* x_q      = (const float*)d_in[0];
    const float* x_k      = (const float*)d_in[1];
    const float* pair     = (const float*)d_in[4];
    const float* scq      = (const float*)d_in[5];
    const float* sck      = (const float*)d_in[6];
    const float* q_cond_w = (const float*)d_in[7];
    const float* q_scale_w= (const float*)d_in[8];
    const float* q_scale_b= (const float*)d_in[9];
    const float* q_bias_w = (const float*)d_in[10];
    const float* k_cond_w = (const float*)d_in[11];
    const float* k_scale_w= (const float*)d_in[12];
    const float* k_scale_b= (const float*)d_in[13];
    const float* k_bias_w = (const float*)d_in[14];
    const float* wq       = (const float*)d_in[15];
    const float* bq       = (const float*)d_in[16];
    const float* wk       = (const float*)d_in[17];
    const float* wv       = (const float*)d_in[18];
    const float* wg       = (const float*)d_in[19];
    const float* azi_wt   = (const float*)d_in[20];
    const float* azi_wc   = (const float*)d_in[21];
    const float* azi_bc   = (const float*)d_in[22];
    const float* t_cond_w = (const float*)d_in[23];
    const float* t_scale_w= (const float*)d_in[24];
    const float* t_scale_b= (const float*)d_in[25];
    const float* t_bias_w = (const float*)d_in[26];
    const float* glu1     = (const float*)d_in[27];
    const float* glu2     = (const float*)d_in[28];
    const float* t_azi_wt = (const float*)d_in[29];
    const float* t_azi_wc = (const float*)d_in[30];
    const float* t_azi_bc = (const float*)d_in[31];

    float* out = (float*)d_out;
    u16* qs   = (u16*)d_ws;                  // bf16 [16][2048][16]   1MB
    u16* ks   = qs + 524288;                 // 1MB
    u16* vt   = ks + 524288;                 // bf16 [16][16][2048]   1MB
    u16* gate = vt + 524288;                 // bf16 [4096][128]      1MB
    u16* aob  = gate + 524288;               // bf16 [4096][128]      1MB
    u16* wT   = aob + 524288;                // bf16 weights (fragment-major) 0.8MB

    prep_kernel<<<152, 256, 0, stream>>>(
        q_scale_w, q_bias_w, wq, wg, k_scale_w, k_bias_w, wk, wv,
        azi_wt, azi_wc, t_scale_w, t_bias_w, t_azi_wc, glu1, glu2, t_azi_wt, wT);
    adaln_mfma<<<256, 512, 0, stream>>>(
        x_q, scq, x_k, sck, q_cond_w, q_scale_b, bq, k_cond_w, k_scale_b,
        wT, qs, ks, vt, gate);
    attn_kernel<<<B_ * H_ * (N_ / 32), 512, 0, stream>>>(qs, ks, vt, pair, gate, aob);
    post_trans<<<NROW / 16, 512, 0, stream>>>(
        aob, scq, x_q, azi_bc, t_cond_w, t_scale_b, t_azi_bc, wT, out);
}